// Round 6
// baseline (7190.148 us; speedup 1.0000x reference)
//
#include <hip/hip_runtime.h>
#include <hip/hip_bf16.h>

#define S_SPK 2
#define BATCH 16
#define TMAX 300
#define CLASSES 3000
#define NUM_STATES 400
#define NUM_ARCS 1200
#define DEN_STATES 3000
#define DEN_ARCS 60000

#define BLK 512               // threads per forward block (8 waves)
#define KCH 6                 // den chunks per sequence
#define CHSTATES 500          // 3000 / 6
#define NSEQ 32               // S_SPK * BATCH
#define NUM_CAP_G 2400        // per graph: 1200 + 3*400
#define NGRAPH 32             // (p,b) graphs

// ---------------- workspace layout (bytes) ----------------
#define WS_DEN_ARCS   0              // 72000*8   = 576000
#define WS_NUM_ARCS   576000         // 32*2400*8 = 614400 -> 1190400
#define WS_DEN_CNT    1190400        // 3000*4    -> 1202400
#define WS_DEN_R      1202400        // 3001*4    -> 1214416 (pad)
#define WS_DEN_CUR    1214416        // 3000*4    -> 1226416
#define WS_NUM_CNT    1226416        // 32*400*4  -> 1277616
#define WS_NUM_R      1277616        // 32*401*4  -> 1328944
#define WS_NUM_CUR    1328944        // 32*400*4  -> 1380144
#define WS_GALPHA     1380144        // 32*2*3000*4 = 768000 -> 2148144
#define WS_FLAGS      2148144        // 32*6*16*4 = 12288 -> 2160432 (64B/flag)
#define WS_DEN_Z      2160432        // 32 floats -> 2160560
#define WS_NUM_Z      2160560        // 64 floats -> 2160816
#define WS_ZERO_INTS  (2160432 / 4)  // zero everything below den_z

// ---------------------------------------------------------------------------
__global__ void zero_ws(int* __restrict__ p, int n) {
    int i = blockIdx.x * blockDim.x + threadIdx.x;
    for (; i < n; i += gridDim.x * blockDim.x) p[i] = 0;
}

__global__ void hist_den(const int* __restrict__ dst, int* __restrict__ cnt) {
    int i = blockIdx.x * blockDim.x + threadIdx.x;
    if (i < DEN_ARCS) atomicAdd(&cnt[dst[i]], 1);
}

__global__ void hist_num(const int* __restrict__ dst, int* __restrict__ cnt) {
    int i = blockIdx.x * blockDim.x + threadIdx.x;
    if (i < NGRAPH * NUM_ARCS) {
        int g = i / NUM_ARCS;
        atomicAdd(&cnt[g * NUM_STATES + dst[i]], 1);
    }
}

// one block, 1024 threads: per-STATE x4-padded prefix for den CSR
__global__ void scan_den(const int* __restrict__ cnt, int* __restrict__ R) {
    __shared__ int sc[1024];
    int tid = threadIdx.x;
    int c0 = 0, c1 = 0, c2 = 0, p0 = 0, p1 = 0, p2 = 0, pg = 0;
    if (tid < 1000) {
        c0 = cnt[3 * tid]; c1 = cnt[3 * tid + 1]; c2 = cnt[3 * tid + 2];
        p0 = (c0 + 3) & ~3; p1 = (c1 + 3) & ~3; p2 = (c2 + 3) & ~3;
        pg = p0 + p1 + p2;
    }
    sc[tid] = pg; __syncthreads();
    for (int o = 1; o < 1024; o <<= 1) {
        int v = (tid >= o) ? sc[tid - o] : 0;
        __syncthreads(); sc[tid] += v; __syncthreads();
    }
    int ex = sc[tid] - pg;
    if (tid < 1000) {
        R[3 * tid] = ex; R[3 * tid + 1] = ex + p0; R[3 * tid + 2] = ex + p0 + p1;
    }
    if (tid == 1000) R[3000] = ex;  // total
}

// 32 blocks x 512: per-graph padded per-state prefix (num)
__global__ void scan_num(const int* __restrict__ cnt, int* __restrict__ R) {
    __shared__ int sc[512];
    int g = blockIdx.x, tid = threadIdx.x;
    int c = 0, pg = 0;
    if (tid < NUM_STATES) { c = cnt[g * NUM_STATES + tid]; pg = (c + 3) & ~3; }
    sc[tid] = pg; __syncthreads();
    for (int o = 1; o < 512; o <<= 1) {
        int v = (tid >= o) ? sc[tid - o] : 0;
        __syncthreads(); sc[tid] += v; __syncthreads();
    }
    int ex = sc[tid] - pg;
    if (tid <= NUM_STATES) R[g * (NUM_STATES + 1) + tid] = ex;
}

__global__ void scat_den(const int* __restrict__ src, const int* __restrict__ dst,
                         const int* __restrict__ lab, const float* __restrict__ w,
                         const int* __restrict__ R, int* __restrict__ cur,
                         int2* __restrict__ out) {
    int i = blockIdx.x * blockDim.x + threadIdx.x;
    if (i >= DEN_ARCS) return;
    int d = dst[i];
    int pos = R[d] + atomicAdd(&cur[d], 1);
    out[pos] = make_int2(src[i] | (lab[i] << 16), __float_as_int(__expf(w[i])));
}

__global__ void scat_num(const int* __restrict__ src, const int* __restrict__ dst,
                         const int* __restrict__ lab, const float* __restrict__ w,
                         const int* __restrict__ R, int* __restrict__ cur,
                         int2* __restrict__ out) {
    int i = blockIdx.x * blockDim.x + threadIdx.x;
    if (i >= NGRAPH * NUM_ARCS) return;
    int g = i / NUM_ARCS;
    int d = dst[i];
    int pos = R[g * (NUM_STATES + 1) + d] + atomicAdd(&cur[g * NUM_STATES + d], 1);
    out[g * NUM_CAP_G + pos] =
        make_int2(src[i] | (lab[i] << 16), __float_as_int(__expf(w[i])));
}

// ---------------------------------------------------------------------------
// num forward: single 512-thread block, prob domain, 1 state/thread
// ---------------------------------------------------------------------------
__device__ __forceinline__ void num_fwd(
    const int* __restrict__ R, const int2* __restrict__ arcs,
    const float* __restrict__ start, const float* __restrict__ fin,
    const float* __restrict__ est, int L, float* __restrict__ out,
    float* A0, float* A1, float* p, float* red)
{
    const int tid = threadIdx.x, lane = tid & 63, wid = tid >> 6;

    if (tid < NUM_STATES) A0[tid] = __expf(start[tid]);

    int rs = 0, re = 0;
    if (tid < NUM_STATES) { rs = R[tid]; re = R[tid + 1]; }

    float l0 = est[tid], l1 = est[tid + 512], l2 = est[tid + 1024];
    float l3 = est[tid + 1536], l4 = est[tid + 2048];
    float l5 = (tid < 440) ? est[tid + 2560] : 0.f;

    float c = 1.f, OFF = 0.f, pend = 0.f;
    const int4* arcs4 = (const int4*)arcs;

    for (int t = 0; t < L; ++t) {
        OFF += pend;
        p[tid] = __expf(l0) * c;        p[tid + 512] = __expf(l1) * c;
        p[tid + 1024] = __expf(l2) * c; p[tid + 1536] = __expf(l3) * c;
        p[tid + 2048] = __expf(l4) * c;
        if (tid < 440) p[tid + 2560] = __expf(l5) * c;
        {
            const float* nr = est + (size_t)((t + 1 < L) ? (t + 1) : t) * CLASSES;
            l0 = nr[tid]; l1 = nr[tid + 512]; l2 = nr[tid + 1024];
            l3 = nr[tid + 1536]; l4 = nr[tid + 2048];
            if (tid < 440) l5 = nr[tid + 2560];
        }
        __syncthreads();

        const float* Ac = (t & 1) ? A1 : A0;
        float*       An = (t & 1) ? A0 : A1;
        float a0 = 0.f;
        for (int r = rs; r < re; r += 4) {
            int4 q0 = arcs4[(r >> 1)];
            int4 q1 = arcs4[(r >> 1) + 1];
            a0 += Ac[q0.x & 0xffff] * p[((unsigned)q0.x) >> 16] * __int_as_float(q0.y);
            a0 += Ac[q0.z & 0xffff] * p[((unsigned)q0.z) >> 16] * __int_as_float(q0.w);
            a0 += Ac[q1.x & 0xffff] * p[((unsigned)q1.x) >> 16] * __int_as_float(q1.y);
            a0 += Ac[q1.z & 0xffff] * p[((unsigned)q1.z) >> 16] * __int_as_float(q1.w);
        }
        float mymax = 0.f;
        if (tid < NUM_STATES) { An[tid] = a0; mymax = a0; }
        #pragma unroll
        for (int o = 32; o > 0; o >>= 1) mymax = fmaxf(mymax, __shfl_down(mymax, o, 64));
        if (lane == 0) red[wid] = mymax;
        __syncthreads();
        if (tid < 64) {
            float v = (tid < 8) ? red[tid] : 0.f;
            #pragma unroll
            for (int o = 4; o > 0; o >>= 1) v = fmaxf(v, __shfl_down(v, o, 64));
            if (tid == 0) red[16] = fmaxf(v, 1e-37f);
        }
        __syncthreads();
        float M = red[16];
        c = 1.0f / M;
        pend = __logf(M);
        __syncthreads();   // red[16] consumed before next overwrite
    }

    const float* Af = (L & 1) ? A1 : A0;
    float fs = 0.f;
    if (tid < NUM_STATES) fs = Af[tid] * __expf(fin[tid]);
    #pragma unroll
    for (int o = 32; o > 0; o >>= 1) fs += __shfl_down(fs, o, 64);
    if (lane == 0) red[wid] = fs;
    __syncthreads();
    if (tid == 0) {
        float s = 0.f;
        #pragma unroll
        for (int k = 0; k < 8; ++k) s += red[k];
        out[0] = OFF + __logf(s);
    }
}

// ---------------------------------------------------------------------------
// Fused forward: blocks [0,192) = den chunk*32+seq; [192,256) = num.
// Den: k=6 chunks exchange alpha per step via LLC.
// Sync: per-chunk 64B-padded release flags (no RMW), all-wave parallel poll,
// 2 barriers/step, consumer-side global max.
// ---------------------------------------------------------------------------
__global__ __launch_bounds__(BLK) void forward_kernel(
    const float* __restrict__ est, const int* __restrict__ seqlen,
    const int2* __restrict__ den_arcs, const int* __restrict__ den_R,
    const float* __restrict__ den_start, const float* __restrict__ den_final,
    const int2* __restrict__ num_arcs, const int* __restrict__ num_R,
    const float* __restrict__ num_start, const float* __restrict__ num_final,
    float* __restrict__ galpha, unsigned* __restrict__ flags,
    float* __restrict__ den_z, float* __restrict__ num_z)
{
    __shared__ float S1[DEN_STATES];   // den: alpha_prev | num: A0 (+A1 at 1536)
    __shared__ float S2[CLASSES];      // p
    __shared__ float red[20];

    const int blk = blockIdx.x;
    const int tid = threadIdx.x, lane = tid & 63, wid = tid >> 6;

    if (blk < KCH * NSEQ) {
        const int seq = blk & 31;        // chunks of a seq share XCD (blk%8 = seq%8)
        const int chunk = blk >> 5;
        const int b = seq & 15;
        const int L = seqlen[b];
        const float* est_base = est + (size_t)seq * TMAX * CLASSES;
        const int base = chunk * CHSTATES;
        unsigned* myflag = &flags[(seq * KCH + chunk) * 16];
        const unsigned* flbase = &flags[seq * KCH * 16];

        int rs = 0, re = 0;
        if (tid < CHSTATES) { rs = den_R[base + tid]; re = den_R[base + tid + 1]; }

        float l0 = est_base[tid], l1 = est_base[tid + 512], l2 = est_base[tid + 1024];
        float l3 = est_base[tid + 1536], l4 = est_base[tid + 2048];
        float l5 = (tid < 440) ? est_base[tid + 2560] : 0.f;

        float OFF = 0.f;
        const int4* arcs4 = (const int4*)den_arcs;

        for (int t = 0; t < L; ++t) {
            // stage p_raw = exp(llh); prefetch next row (overlaps poll)
            S2[tid] = __expf(l0);        S2[tid + 512] = __expf(l1);
            S2[tid + 1024] = __expf(l2); S2[tid + 1536] = __expf(l3);
            S2[tid + 2048] = __expf(l4);
            if (tid < 440) S2[tid + 2560] = __expf(l5);
            {
                const float* nr = est_base + (size_t)((t + 1 < L) ? (t + 1) : t) * CLASSES;
                l0 = nr[tid]; l1 = nr[tid + 512]; l2 = nr[tid + 1024];
                l3 = nr[tid + 1536]; l4 = nr[tid + 2048];
                if (tid < 440) l5 = nr[tid + 2560];
            }

            float cM;
            if (t == 0) {
                S1[tid] = __expf(den_start[tid]);
                S1[tid + 512] = __expf(den_start[tid + 512]);
                S1[tid + 1024] = __expf(den_start[tid + 1024]);
                S1[tid + 1536] = __expf(den_start[tid + 1536]);
                S1[tid + 2048] = __expf(den_start[tid + 2048]);
                if (tid < 440) S1[tid + 2560] = __expf(den_start[tid + 2560]);
                cM = 1.0f;
                __syncthreads();                               // B (S1,S2 ready)
            } else {
                // all-wave parallel poll: lanes 0..5 spin on the 6 flags
                const unsigned tgt = (unsigned)t;
                if (lane < KCH) {
                    const unsigned* fp = &flbase[lane * 16];
                    while (__hip_atomic_load(fp, __ATOMIC_ACQUIRE,
                                             __HIP_MEMORY_SCOPE_AGENT) < tgt)
                        __builtin_amdgcn_s_sleep(1);
                }
                // wave exits loop only when all 6 flags >= t
                const float* gaP = galpha + ((size_t)seq * 2 + ((t - 1) & 1)) * DEN_STATES;
                float x0 = __hip_atomic_load(&gaP[tid], __ATOMIC_RELAXED, __HIP_MEMORY_SCOPE_AGENT);
                float x1 = __hip_atomic_load(&gaP[tid + 512], __ATOMIC_RELAXED, __HIP_MEMORY_SCOPE_AGENT);
                float x2 = __hip_atomic_load(&gaP[tid + 1024], __ATOMIC_RELAXED, __HIP_MEMORY_SCOPE_AGENT);
                float x3 = __hip_atomic_load(&gaP[tid + 1536], __ATOMIC_RELAXED, __HIP_MEMORY_SCOPE_AGENT);
                float x4 = __hip_atomic_load(&gaP[tid + 2048], __ATOMIC_RELAXED, __HIP_MEMORY_SCOPE_AGENT);
                float x5 = (tid < 440)
                    ? __hip_atomic_load(&gaP[tid + 2560], __ATOMIC_RELAXED, __HIP_MEMORY_SCOPE_AGENT)
                    : 0.f;
                S1[tid] = x0; S1[tid + 512] = x1; S1[tid + 1024] = x2;
                S1[tid + 1536] = x3; S1[tid + 2048] = x4;
                if (tid < 440) S1[tid + 2560] = x5;
                // consumer-side global max (identical in every chunk)
                float mymax = fmaxf(fmaxf(fmaxf(x0, x1), fmaxf(x2, x3)), fmaxf(x4, x5));
                #pragma unroll
                for (int o = 32; o > 0; o >>= 1)
                    mymax = fmaxf(mymax, __shfl_down(mymax, o, 64));
                if (lane == 0) red[wid] = mymax;
                __syncthreads();                               // B (S1, S2, red ready)
                float M = red[0];
                #pragma unroll
                for (int k = 1; k < 8; ++k) M = fmaxf(M, red[k]);
                M = fmaxf(M, 1e-37f);
                cM = 1.0f / M;
                OFF += __logf(M);
            }

            float acc = 0.f;
            for (int r = rs; r < re; r += 4) {
                int4 q0 = arcs4[(r >> 1)];
                int4 q1 = arcs4[(r >> 1) + 1];
                acc += S1[q0.x & 0xffff] * S2[((unsigned)q0.x) >> 16] * __int_as_float(q0.y);
                acc += S1[q0.z & 0xffff] * S2[((unsigned)q0.z) >> 16] * __int_as_float(q0.w);
                acc += S1[q1.x & 0xffff] * S2[((unsigned)q1.x) >> 16] * __int_as_float(q1.y);
                acc += S1[q1.z & 0xffff] * S2[((unsigned)q1.z) >> 16] * __int_as_float(q1.w);
            }
            float val = acc * cM;

            float* gaW = galpha + ((size_t)seq * 2 + (t & 1)) * DEN_STATES;
            if (tid < CHSTATES)
                __hip_atomic_store(&gaW[base + tid], val, __ATOMIC_RELAXED,
                                   __HIP_MEMORY_SCOPE_AGENT);   // contiguous/coalesced
            __syncthreads();        // C: stores drained (vmcnt(0) before s_barrier)
            if (tid == 0)
                __hip_atomic_store(myflag, (unsigned)(t + 1), __ATOMIC_RELEASE,
                                   __HIP_MEMORY_SCOPE_AGENT);
        }

        // epilogue: chunk 0 computes logZ from final buffer
        if (chunk == 0) {
            const unsigned tgt = (unsigned)L;
            if (lane < KCH) {
                const unsigned* fp = &flbase[lane * 16];
                while (__hip_atomic_load(fp, __ATOMIC_ACQUIRE,
                                         __HIP_MEMORY_SCOPE_AGENT) < tgt)
                    __builtin_amdgcn_s_sleep(1);
            }
            const float* gaF = galpha + ((size_t)seq * 2 + ((L - 1) & 1)) * DEN_STATES;
            float fs = 0.f;
            fs += __hip_atomic_load(&gaF[tid], __ATOMIC_RELAXED, __HIP_MEMORY_SCOPE_AGENT) * __expf(den_final[tid]);
            fs += __hip_atomic_load(&gaF[tid + 512], __ATOMIC_RELAXED, __HIP_MEMORY_SCOPE_AGENT) * __expf(den_final[tid + 512]);
            fs += __hip_atomic_load(&gaF[tid + 1024], __ATOMIC_RELAXED, __HIP_MEMORY_SCOPE_AGENT) * __expf(den_final[tid + 1024]);
            fs += __hip_atomic_load(&gaF[tid + 1536], __ATOMIC_RELAXED, __HIP_MEMORY_SCOPE_AGENT) * __expf(den_final[tid + 1536]);
            fs += __hip_atomic_load(&gaF[tid + 2048], __ATOMIC_RELAXED, __HIP_MEMORY_SCOPE_AGENT) * __expf(den_final[tid + 2048]);
            if (tid < 440)
                fs += __hip_atomic_load(&gaF[tid + 2560], __ATOMIC_RELAXED, __HIP_MEMORY_SCOPE_AGENT) * __expf(den_final[tid + 2560]);
            #pragma unroll
            for (int o = 32; o > 0; o >>= 1) fs += __shfl_down(fs, o, 64);
            if (lane == 0) red[wid] = fs;
            __syncthreads();
            if (tid == 0) {
                float s = 0.f;
                #pragma unroll
                for (int k = 0; k < 8; ++k) s += red[k];
                den_z[seq] = OFF + __logf(s);
            }
        }
    } else {
        const int q = blk - KCH * NSEQ;
        const int b = q & 15;
        const int sp = q >> 4;
        const int s = sp >> 1, pp = sp & 1;
        const int L = seqlen[b];
        const int g = pp * BATCH + b;
        num_fwd(num_R + (size_t)g * (NUM_STATES + 1),
                num_arcs + (size_t)g * NUM_CAP_G,
                num_start + (size_t)g * NUM_STATES,
                num_final + (size_t)g * NUM_STATES,
                est + (size_t)(s * BATCH + b) * TMAX * CLASSES, L, &num_z[q],
                S1, S1 + 1536, S2, red);
    }
}

// ---------------------------------------------------------------------------
__global__ void loss_kernel(const float* __restrict__ den_z,
                            const float* __restrict__ num_z,
                            float* __restrict__ out)
{
    int tid = threadIdx.x;
    float l = 0.f;
    if (tid < BATCH) {
        int b = tid;
        float z00 = num_z[(0 * 2 + 0) * BATCH + b];
        float z01 = num_z[(0 * 2 + 1) * BATCH + b];
        float z10 = num_z[(1 * 2 + 0) * BATCH + b];
        float z11 = num_z[(1 * 2 + 1) * BATCH + b];
        float perm0 = z00 + z11;
        float perm1 = z01 + z10;
        float n0, n1;
        if (perm0 >= perm1) { n0 = z00; n1 = z11; }
        else                { n0 = z01; n1 = z10; }
        l = -(n0 - den_z[0 * BATCH + b]) - (n1 - den_z[1 * BATCH + b]);
    }
    #pragma unroll
    for (int o = 32; o > 0; o >>= 1) l += __shfl_down(l, o, 64);
    if (tid == 0) out[0] = l;
}

// ---------------------------------------------------------------------------
extern "C" void kernel_launch(void* const* d_in, const int* in_sizes, int n_in,
                              void* d_out, int out_size, void* d_ws, size_t ws_size,
                              hipStream_t stream) {
    const float* est        = (const float*)d_in[0];
    const int*   seqlen     = (const int*)d_in[1];
    const int*   num_src    = (const int*)d_in[2];
    const int*   num_dst    = (const int*)d_in[3];
    const int*   num_label  = (const int*)d_in[4];
    const float* num_weight = (const float*)d_in[5];
    const float* num_start  = (const float*)d_in[6];
    const float* num_final  = (const float*)d_in[7];
    const int*   den_src    = (const int*)d_in[8];
    const int*   den_dst    = (const int*)d_in[9];
    const int*   den_label  = (const int*)d_in[10];
    const float* den_weight = (const float*)d_in[11];
    const float* den_start  = (const float*)d_in[12];
    const float* den_final  = (const float*)d_in[13];

    char* ws = (char*)d_ws;
    int2*     den_arcs = (int2*)(ws + WS_DEN_ARCS);
    int2*     num_arcs = (int2*)(ws + WS_NUM_ARCS);
    int*      den_cnt  = (int*)(ws + WS_DEN_CNT);
    int*      den_R    = (int*)(ws + WS_DEN_R);
    int*      den_cur  = (int*)(ws + WS_DEN_CUR);
    int*      num_cnt  = (int*)(ws + WS_NUM_CNT);
    int*      num_R    = (int*)(ws + WS_NUM_R);
    int*      num_cur  = (int*)(ws + WS_NUM_CUR);
    float*    galpha   = (float*)(ws + WS_GALPHA);
    unsigned* flags    = (unsigned*)(ws + WS_FLAGS);
    float*    den_z    = (float*)(ws + WS_DEN_Z);
    float*    num_z    = (float*)(ws + WS_NUM_Z);

    zero_ws<<<512, 256, 0, stream>>>((int*)ws, WS_ZERO_INTS);
    hist_den<<<(DEN_ARCS + 255) / 256, 256, 0, stream>>>(den_dst, den_cnt);
    hist_num<<<(NGRAPH * NUM_ARCS + 255) / 256, 256, 0, stream>>>(num_dst, num_cnt);
    scan_den<<<1, 1024, 0, stream>>>(den_cnt, den_R);
    scan_num<<<NGRAPH, 512, 0, stream>>>(num_cnt, num_R);
    scat_den<<<(DEN_ARCS + 255) / 256, 256, 0, stream>>>(
        den_src, den_dst, den_label, den_weight, den_R, den_cur, den_arcs);
    scat_num<<<(NGRAPH * NUM_ARCS + 255) / 256, 256, 0, stream>>>(
        num_src, num_dst, num_label, num_weight, num_R, num_cur, num_arcs);

    forward_kernel<<<KCH * NSEQ + S_SPK * S_SPK * BATCH, BLK, 0, stream>>>(
        est, seqlen, den_arcs, den_R, den_start, den_final,
        num_arcs, num_R, num_start, num_final,
        galpha, flags, den_z, num_z);

    loss_kernel<<<1, 64, 0, stream>>>(den_z, num_z, (float*)d_out);
}

// Round 7
// 2154.040 us; speedup vs baseline: 3.3380x; 3.3380x over previous
//
#include <hip/hip_runtime.h>
#include <hip/hip_bf16.h>

#define S_SPK 2
#define BATCH 16
#define TMAX 300
#define CLASSES 3000
#define NUM_STATES 400
#define NUM_ARCS 1200
#define DEN_STATES 3000
#define DEN_ARCS 60000

#define BLK 768               // threads per forward block (12 waves)
#define NWAVE 12
#define KCH 4                 // den chunks per sequence
#define CHST 750              // 3000 / 4
#define NSEQ 32               // S_SPK * BATCH
#define NUM_CAP_G 2400        // per graph: 1200 + 3*400
#define NGRAPH 32             // (p,b) graphs

// ---------------- workspace layout (bytes) ----------------
#define WS_DEN_ARCS   0              // 72000*8   = 576000
#define WS_NUM_ARCS   576000         // 32*2400*8 = 614400 -> 1190400
#define WS_DEN_CNT    1190400        // 3000*4    -> 1202400
#define WS_DEN_R      1202400        // 3001*4    -> 1214416 (pad)
#define WS_DEN_CUR    1214416        // 3000*4    -> 1226416
#define WS_NUM_CNT    1226416        // 32*400*4  -> 1277616
#define WS_NUM_R      1277616        // 32*401*4  -> 1328944
#define WS_NUM_CUR    1328944        // 32*400*4  -> 1380144
#define WS_GALPHA     1380144        // 32*2*3000*4 = 768000 -> 2148144
#define WS_FLAGS      2148144        // 32*4*16*4 = 8192 -> 2156336 (64B/flag)
#define WS_DEN_Z      2156336        // 32 floats -> 2156464
#define WS_NUM_Z      2156464        // 64 floats -> 2156720
#define WS_ZERO_INTS  (2156336 / 4)  // zero everything below den_z

// ---------------------------------------------------------------------------
__global__ void zero_ws(int* __restrict__ p, int n) {
    int i = blockIdx.x * blockDim.x + threadIdx.x;
    for (; i < n; i += gridDim.x * blockDim.x) p[i] = 0;
}

__global__ void hist_den(const int* __restrict__ dst, int* __restrict__ cnt) {
    int i = blockIdx.x * blockDim.x + threadIdx.x;
    if (i < DEN_ARCS) atomicAdd(&cnt[dst[i]], 1);
}

__global__ void hist_num(const int* __restrict__ dst, int* __restrict__ cnt) {
    int i = blockIdx.x * blockDim.x + threadIdx.x;
    if (i < NGRAPH * NUM_ARCS) {
        int g = i / NUM_ARCS;
        atomicAdd(&cnt[g * NUM_STATES + dst[i]], 1);
    }
}

// one block, 1024 threads: per-STATE x4-padded prefix for den CSR
__global__ void scan_den(const int* __restrict__ cnt, int* __restrict__ R) {
    __shared__ int sc[1024];
    int tid = threadIdx.x;
    int c0 = 0, c1 = 0, c2 = 0, p0 = 0, p1 = 0, p2 = 0, pg = 0;
    if (tid < 1000) {
        c0 = cnt[3 * tid]; c1 = cnt[3 * tid + 1]; c2 = cnt[3 * tid + 2];
        p0 = (c0 + 3) & ~3; p1 = (c1 + 3) & ~3; p2 = (c2 + 3) & ~3;
        pg = p0 + p1 + p2;
    }
    sc[tid] = pg; __syncthreads();
    for (int o = 1; o < 1024; o <<= 1) {
        int v = (tid >= o) ? sc[tid - o] : 0;
        __syncthreads(); sc[tid] += v; __syncthreads();
    }
    int ex = sc[tid] - pg;
    if (tid < 1000) {
        R[3 * tid] = ex; R[3 * tid + 1] = ex + p0; R[3 * tid + 2] = ex + p0 + p1;
    }
    if (tid == 1000) R[3000] = ex;  // total
}

// 32 blocks x 512: per-graph padded per-state prefix (num)
__global__ void scan_num(const int* __restrict__ cnt, int* __restrict__ R) {
    __shared__ int sc[512];
    int g = blockIdx.x, tid = threadIdx.x;
    int c = 0, pg = 0;
    if (tid < NUM_STATES) { c = cnt[g * NUM_STATES + tid]; pg = (c + 3) & ~3; }
    sc[tid] = pg; __syncthreads();
    for (int o = 1; o < 512; o <<= 1) {
        int v = (tid >= o) ? sc[tid - o] : 0;
        __syncthreads(); sc[tid] += v; __syncthreads();
    }
    int ex = sc[tid] - pg;
    if (tid <= NUM_STATES) R[g * (NUM_STATES + 1) + tid] = ex;
}

__global__ void scat_den(const int* __restrict__ src, const int* __restrict__ dst,
                         const int* __restrict__ lab, const float* __restrict__ w,
                         const int* __restrict__ R, int* __restrict__ cur,
                         int2* __restrict__ out) {
    int i = blockIdx.x * blockDim.x + threadIdx.x;
    if (i >= DEN_ARCS) return;
    int d = dst[i];
    int pos = R[d] + atomicAdd(&cur[d], 1);
    out[pos] = make_int2(src[i] | (lab[i] << 16), __float_as_int(__expf(w[i])));
}

__global__ void scat_num(const int* __restrict__ src, const int* __restrict__ dst,
                         const int* __restrict__ lab, const float* __restrict__ w,
                         const int* __restrict__ R, int* __restrict__ cur,
                         int2* __restrict__ out) {
    int i = blockIdx.x * blockDim.x + threadIdx.x;
    if (i >= NGRAPH * NUM_ARCS) return;
    int g = i / NUM_ARCS;
    int d = dst[i];
    int pos = R[g * (NUM_STATES + 1) + d] + atomicAdd(&cur[g * NUM_STATES + d], 1);
    out[g * NUM_CAP_G + pos] =
        make_int2(src[i] | (lab[i] << 16), __float_as_int(__expf(w[i])));
}

// ---------------------------------------------------------------------------
// num forward: single 768-thread block, prob domain, 1 state/thread
// ---------------------------------------------------------------------------
__device__ __forceinline__ void num_fwd(
    const int* __restrict__ R, const int2* __restrict__ arcs,
    const float* __restrict__ start, const float* __restrict__ fin,
    const float* __restrict__ est, int L, float* __restrict__ out,
    float* A0, float* A1, float* p, float* red)
{
    const int tid = threadIdx.x, lane = tid & 63, wid = tid >> 6;

    if (tid < NUM_STATES) A0[tid] = __expf(start[tid]);

    int rs = 0, re = 0;
    if (tid < NUM_STATES) { rs = R[tid]; re = R[tid + 1]; }

    float l0 = est[tid], l1 = est[tid + 768], l2 = est[tid + 1536];
    float l3 = (tid < 696) ? est[tid + 2304] : 0.f;

    float c = 1.f, OFF = 0.f, pend = 0.f;
    const int4* arcs4 = (const int4*)arcs;

    for (int t = 0; t < L; ++t) {
        OFF += pend;
        p[tid] = __expf(l0) * c;        p[tid + 768] = __expf(l1) * c;
        p[tid + 1536] = __expf(l2) * c;
        if (tid < 696) p[tid + 2304] = __expf(l3) * c;
        {
            const float* nr = est + (size_t)((t + 1 < L) ? (t + 1) : t) * CLASSES;
            l0 = nr[tid]; l1 = nr[tid + 768]; l2 = nr[tid + 1536];
            if (tid < 696) l3 = nr[tid + 2304];
        }
        __syncthreads();   // p ready (also protects red[] from prev iter reads)

        const float* Ac = (t & 1) ? A1 : A0;
        float*       An = (t & 1) ? A0 : A1;
        float a0 = 0.f;
        for (int r = rs; r < re; r += 4) {
            int4 q0 = arcs4[(r >> 1)];
            int4 q1 = arcs4[(r >> 1) + 1];
            a0 += Ac[q0.x & 0xffff] * p[((unsigned)q0.x) >> 16] * __int_as_float(q0.y);
            a0 += Ac[q0.z & 0xffff] * p[((unsigned)q0.z) >> 16] * __int_as_float(q0.w);
            a0 += Ac[q1.x & 0xffff] * p[((unsigned)q1.x) >> 16] * __int_as_float(q1.y);
            a0 += Ac[q1.z & 0xffff] * p[((unsigned)q1.z) >> 16] * __int_as_float(q1.w);
        }
        float mymax = 0.f;
        if (tid < NUM_STATES) { An[tid] = a0; mymax = a0; }
        #pragma unroll
        for (int o = 32; o > 0; o >>= 1) mymax = fmaxf(mymax, __shfl_down(mymax, o, 64));
        if (lane == 0) red[wid] = mymax;
        __syncthreads();
        float M = red[0];
        #pragma unroll
        for (int k = 1; k < NWAVE; ++k) M = fmaxf(M, red[k]);
        M = fmaxf(M, 1e-37f);
        c = 1.0f / M;
        pend = __logf(M);
    }

    const float* Af = (L & 1) ? A1 : A0;
    float fs = 0.f;
    if (tid < NUM_STATES) fs = Af[tid] * __expf(fin[tid]);
    __syncthreads();   // red[] settled
    #pragma unroll
    for (int o = 32; o > 0; o >>= 1) fs += __shfl_down(fs, o, 64);
    if (lane == 0) red[wid] = fs;
    __syncthreads();
    if (tid == 0) {
        float s = 0.f;
        #pragma unroll
        for (int k = 0; k < NWAVE; ++k) s += red[k];
        out[0] = OFF + __logf(s);
    }
}

// ---------------------------------------------------------------------------
// Fused forward: blocks [0,128) = den chunk*32+seq; [128,192) = num.
// Den: k=4 chunks exchange alpha per step via LLC.
// Sync: per-chunk 64B release flags (no RMW); wave-0-only poll + barrier wake.
// ---------------------------------------------------------------------------
__global__ __launch_bounds__(BLK) void forward_kernel(
    const float* __restrict__ est, const int* __restrict__ seqlen,
    const int2* __restrict__ den_arcs, const int* __restrict__ den_R,
    const float* __restrict__ den_start, const float* __restrict__ den_final,
    const int2* __restrict__ num_arcs, const int* __restrict__ num_R,
    const float* __restrict__ num_start, const float* __restrict__ num_final,
    float* __restrict__ galpha, unsigned* __restrict__ flags,
    float* __restrict__ den_z, float* __restrict__ num_z)
{
    __shared__ float S1[DEN_STATES];   // den: alpha_prev | num: A0 (+A1 at 1536)
    __shared__ float S2[CLASSES];      // p
    __shared__ float red[16];

    const int blk = blockIdx.x;
    const int tid = threadIdx.x, lane = tid & 63, wid = tid >> 6;

    if (blk < KCH * NSEQ) {
        const int seq = blk & 31;        // chunks of a seq share XCD residue
        const int chunk = blk >> 5;
        const int b = seq & 15;
        const int L = seqlen[b];
        const float* est_base = est + (size_t)seq * TMAX * CLASSES;
        const int base = chunk * CHST;
        unsigned* myflag = &flags[(seq * KCH + chunk) * 16];
        const unsigned* flbase = &flags[seq * KCH * 16];

        int rs = 0, re = 0;
        if (tid < CHST) { rs = den_R[base + tid]; re = den_R[base + tid + 1]; }

        float l0 = est_base[tid], l1 = est_base[tid + 768], l2 = est_base[tid + 1536];
        float l3 = (tid < 696) ? est_base[tid + 2304] : 0.f;

        float OFF = 0.f;
        const int4* arcs4 = (const int4*)den_arcs;

        for (int t = 0; t < L; ++t) {
            // stage p_raw = exp(llh); prefetch next row (overlaps poll)
            S2[tid] = __expf(l0); S2[tid + 768] = __expf(l1); S2[tid + 1536] = __expf(l2);
            if (tid < 696) S2[tid + 2304] = __expf(l3);
            {
                const float* nr = est_base + (size_t)((t + 1 < L) ? (t + 1) : t) * CLASSES;
                l0 = nr[tid]; l1 = nr[tid + 768]; l2 = nr[tid + 1536];
                if (tid < 696) l3 = nr[tid + 2304];
            }

            float cM;
            if (t == 0) {
                S1[tid] = __expf(den_start[tid]);
                S1[tid + 768] = __expf(den_start[tid + 768]);
                S1[tid + 1536] = __expf(den_start[tid + 1536]);
                if (tid < 696) S1[tid + 2304] = __expf(den_start[tid + 2304]);
                cM = 1.0f;
                __syncthreads();                               // B (S1,S2 ready)
            } else {
                // wave-0-only poll: lanes 0..3 spin on the 4 flags
                if (tid < KCH) {
                    const unsigned* fp = &flbase[tid * 16];
                    const unsigned tgt = (unsigned)t;
                    while (__hip_atomic_load(fp, __ATOMIC_ACQUIRE,
                                             __HIP_MEMORY_SCOPE_AGENT) < tgt)
                        __builtin_amdgcn_s_sleep(1);
                }
                __syncthreads();                               // A (flags passed, S2 ready)
                const float* gaP = galpha + ((size_t)seq * 2 + ((t - 1) & 1)) * DEN_STATES;
                float x0 = __hip_atomic_load(&gaP[tid], __ATOMIC_RELAXED, __HIP_MEMORY_SCOPE_AGENT);
                float x1 = __hip_atomic_load(&gaP[tid + 768], __ATOMIC_RELAXED, __HIP_MEMORY_SCOPE_AGENT);
                float x2 = __hip_atomic_load(&gaP[tid + 1536], __ATOMIC_RELAXED, __HIP_MEMORY_SCOPE_AGENT);
                float x3 = (tid < 696)
                    ? __hip_atomic_load(&gaP[tid + 2304], __ATOMIC_RELAXED, __HIP_MEMORY_SCOPE_AGENT)
                    : 0.f;
                S1[tid] = x0; S1[tid + 768] = x1; S1[tid + 1536] = x2;
                if (tid < 696) S1[tid + 2304] = x3;
                // consumer-side global max (identical in every chunk)
                float mymax = fmaxf(fmaxf(x0, x1), fmaxf(x2, x3));
                #pragma unroll
                for (int o = 32; o > 0; o >>= 1)
                    mymax = fmaxf(mymax, __shfl_down(mymax, o, 64));
                if (lane == 0) red[wid] = mymax;
                __syncthreads();                               // B (S1, red ready)
                float M = red[0];
                #pragma unroll
                for (int k = 1; k < NWAVE; ++k) M = fmaxf(M, red[k]);
                M = fmaxf(M, 1e-37f);
                cM = 1.0f / M;
                OFF += __logf(M);
            }

            float acc = 0.f;
            for (int r = rs; r < re; r += 4) {
                int4 q0 = arcs4[(r >> 1)];
                int4 q1 = arcs4[(r >> 1) + 1];
                acc += S1[q0.x & 0xffff] * S2[((unsigned)q0.x) >> 16] * __int_as_float(q0.y);
                acc += S1[q0.z & 0xffff] * S2[((unsigned)q0.z) >> 16] * __int_as_float(q0.w);
                acc += S1[q1.x & 0xffff] * S2[((unsigned)q1.x) >> 16] * __int_as_float(q1.y);
                acc += S1[q1.z & 0xffff] * S2[((unsigned)q1.z) >> 16] * __int_as_float(q1.w);
            }
            float val = acc * cM;

            float* gaW = galpha + ((size_t)seq * 2 + (t & 1)) * DEN_STATES;
            if (tid < CHST)
                __hip_atomic_store(&gaW[base + tid], val, __ATOMIC_RELAXED,
                                   __HIP_MEMORY_SCOPE_AGENT);   // contiguous/coalesced
            __syncthreads();        // C: stores drained (vmcnt(0) before s_barrier)
            if (tid == 0)
                __hip_atomic_store(myflag, (unsigned)(t + 1), __ATOMIC_RELEASE,
                                   __HIP_MEMORY_SCOPE_AGENT);
        }

        // epilogue: chunk 0 computes logZ from final buffer
        if (chunk == 0) {
            if (tid < KCH) {
                const unsigned* fp = &flbase[tid * 16];
                const unsigned tgt = (unsigned)L;
                while (__hip_atomic_load(fp, __ATOMIC_ACQUIRE,
                                         __HIP_MEMORY_SCOPE_AGENT) < tgt)
                    __builtin_amdgcn_s_sleep(1);
            }
            __syncthreads();
            const float* gaF = galpha + ((size_t)seq * 2 + ((L - 1) & 1)) * DEN_STATES;
            float fs = 0.f;
            fs += __hip_atomic_load(&gaF[tid], __ATOMIC_RELAXED, __HIP_MEMORY_SCOPE_AGENT) * __expf(den_final[tid]);
            fs += __hip_atomic_load(&gaF[tid + 768], __ATOMIC_RELAXED, __HIP_MEMORY_SCOPE_AGENT) * __expf(den_final[tid + 768]);
            fs += __hip_atomic_load(&gaF[tid + 1536], __ATOMIC_RELAXED, __HIP_MEMORY_SCOPE_AGENT) * __expf(den_final[tid + 1536]);
            if (tid < 696)
                fs += __hip_atomic_load(&gaF[tid + 2304], __ATOMIC_RELAXED, __HIP_MEMORY_SCOPE_AGENT) * __expf(den_final[tid + 2304]);
            #pragma unroll
            for (int o = 32; o > 0; o >>= 1) fs += __shfl_down(fs, o, 64);
            if (lane == 0) red[wid] = fs;
            __syncthreads();
            if (tid == 0) {
                float s = 0.f;
                #pragma unroll
                for (int k = 0; k < NWAVE; ++k) s += red[k];
                den_z[seq] = OFF + __logf(s);
            }
        }
    } else {
        const int q = blk - KCH * NSEQ;
        const int b = q & 15;
        const int sp = q >> 4;
        const int s = sp >> 1, pp = sp & 1;
        const int L = seqlen[b];
        const int g = pp * BATCH + b;
        num_fwd(num_R + (size_t)g * (NUM_STATES + 1),
                num_arcs + (size_t)g * NUM_CAP_G,
                num_start + (size_t)g * NUM_STATES,
                num_final + (size_t)g * NUM_STATES,
                est + (size_t)(s * BATCH + b) * TMAX * CLASSES, L, &num_z[q],
                S1, S1 + 1536, S2, red);
    }
}

// ---------------------------------------------------------------------------
__global__ void loss_kernel(const float* __restrict__ den_z,
                            const float* __restrict__ num_z,
                            float* __restrict__ out)
{
    int tid = threadIdx.x;
    float l = 0.f;
    if (tid < BATCH) {
        int b = tid;
        float z00 = num_z[(0 * 2 + 0) * BATCH + b];
        float z01 = num_z[(0 * 2 + 1) * BATCH + b];
        float z10 = num_z[(1 * 2 + 0) * BATCH + b];
        float z11 = num_z[(1 * 2 + 1) * BATCH + b];
        float perm0 = z00 + z11;
        float perm1 = z01 + z10;
        float n0, n1;
        if (perm0 >= perm1) { n0 = z00; n1 = z11; }
        else                { n0 = z01; n1 = z10; }
        l = -(n0 - den_z[0 * BATCH + b]) - (n1 - den_z[1 * BATCH + b]);
    }
    #pragma unroll
    for (int o = 32; o > 0; o >>= 1) l += __shfl_down(l, o, 64);
    if (tid == 0) out[0] = l;
}

// ---------------------------------------------------------------------------
extern "C" void kernel_launch(void* const* d_in, const int* in_sizes, int n_in,
                              void* d_out, int out_size, void* d_ws, size_t ws_size,
                              hipStream_t stream) {
    const float* est        = (const float*)d_in[0];
    const int*   seqlen     = (const int*)d_in[1];
    const int*   num_src    = (const int*)d_in[2];
    const int*   num_dst    = (const int*)d_in[3];
    const int*   num_label  = (const int*)d_in[4];
    const float* num_weight = (const float*)d_in[5];
    const float* num_start  = (const float*)d_in[6];
    const float* num_final  = (const float*)d_in[7];
    const int*   den_src    = (const int*)d_in[8];
    const int*   den_dst    = (const int*)d_in[9];
    const int*   den_label  = (const int*)d_in[10];
    const float* den_weight = (const float*)d_in[11];
    const float* den_start  = (const float*)d_in[12];
    const float* den_final  = (const float*)d_in[13];

    char* ws = (char*)d_ws;
    int2*     den_arcs = (int2*)(ws + WS_DEN_ARCS);
    int2*     num_arcs = (int2*)(ws + WS_NUM_ARCS);
    int*      den_cnt  = (int*)(ws + WS_DEN_CNT);
    int*      den_R    = (int*)(ws + WS_DEN_R);
    int*      den_cur  = (int*)(ws + WS_DEN_CUR);
    int*      num_cnt  = (int*)(ws + WS_NUM_CNT);
    int*      num_R    = (int*)(ws + WS_NUM_R);
    int*      num_cur  = (int*)(ws + WS_NUM_CUR);
    float*    galpha   = (float*)(ws + WS_GALPHA);
    unsigned* flags    = (unsigned*)(ws + WS_FLAGS);
    float*    den_z    = (float*)(ws + WS_DEN_Z);
    float*    num_z    = (float*)(ws + WS_NUM_Z);

    zero_ws<<<512, 256, 0, stream>>>((int*)ws, WS_ZERO_INTS);
    hist_den<<<(DEN_ARCS + 255) / 256, 256, 0, stream>>>(den_dst, den_cnt);
    hist_num<<<(NGRAPH * NUM_ARCS + 255) / 256, 256, 0, stream>>>(num_dst, num_cnt);
    scan_den<<<1, 1024, 0, stream>>>(den_cnt, den_R);
    scan_num<<<NGRAPH, 512, 0, stream>>>(num_cnt, num_R);
    scat_den<<<(DEN_ARCS + 255) / 256, 256, 0, stream>>>(
        den_src, den_dst, den_label, den_weight, den_R, den_cur, den_arcs);
    scat_num<<<(NGRAPH * NUM_ARCS + 255) / 256, 256, 0, stream>>>(
        num_src, num_dst, num_label, num_weight, num_R, num_cur, num_arcs);

    forward_kernel<<<KCH * NSEQ + S_SPK * S_SPK * BATCH, BLK, 0, stream>>>(
        est, seqlen, den_arcs, den_R, den_start, den_final,
        num_arcs, num_R, num_start, num_final,
        galpha, flags, den_z, num_z);

    loss_kernel<<<1, 64, 0, stream>>>(den_z, num_z, (float*)d_out);
}